// Round 1
// baseline (929.599 us; speedup 1.0000x reference)
//
#include <hip/hip_runtime.h>
#include <math.h>

#define BB 2
#define SS 2048
#define DD 768
#define HH 12
#define DKK 64
#define BH (BB*HH)

typedef __attribute__((ext_vector_type(8))) __bf16 bf16x8;
typedef __attribute__((ext_vector_type(4))) float floatx4;
typedef unsigned short ushort_t;

__device__ inline float bf2f(ushort_t u) {
    unsigned int x = ((unsigned int)u) << 16;
    return __builtin_bit_cast(float, x);
}
__device__ inline ushort_t f2bf(float f) {
    unsigned int x = __builtin_bit_cast(unsigned int, f);
    unsigned int lsb = (x >> 16) & 1u;
    x += 0x7fffu + lsb;
    return (ushort_t)(x >> 16);
}

template<int ISBF>
__device__ inline float ldf(const void* p, size_t i) {
    if (ISBF) return bf2f(((const ushort_t*)p)[i]);
    else      return ((const float*)p)[i];
}

// ---------------- dtype detection ----------------
// Sample even u16 halves of `query` (N(0,1)). bf16 data: exponent bits in a
// narrow band (~always). fp32 data: these are low mantissa bits (uniform,
// ~12% land in band). Threshold at 128/256.
__global__ void detect_dtype(const ushort_t* __restrict__ q, int* __restrict__ flag) {
    __shared__ int cnt;
    if (threadIdx.x == 0) cnt = 0;
    __syncthreads();
    ushort_t u = q[2 * threadIdx.x];
    int e = (u >> 7) & 0xFF;
    if (e >= 0x66 && e <= 0x84) atomicAdd(&cnt, 1);
    __syncthreads();
    if (threadIdx.x == 0) *flag = (cnt >= 128) ? 1 : 0;
}

// ---------------- transpose weights to K-major (always writes bf16) --------
template<int ISBF>
__device__ void transpose_body(const void* __restrict__ in, ushort_t* __restrict__ out) {
    int t = blockIdx.x * 256 + threadIdx.x;
    if (t >= DD * DD) return;
    int e = t / DD, d = t - e * DD;
    out[t] = f2bf(ldf<ISBF>(in, (size_t)d * DD + e));
}
__global__ void transpose_w(const void* in, ushort_t* out, const int* flag) {
    if (*flag) transpose_body<1>(in, out); else transpose_body<0>(in, out);
}

// ---------------- projection GEMM  C[R,E] = A[R,:] @ W[:,E] + b[E] ----------
template<int ISBF>
__device__ void gemm_body(const void* __restrict__ A, const ushort_t* __restrict__ Wt,
                          const void* __restrict__ bias, ushort_t* __restrict__ outp,
                          ushort_t* lAs, ushort_t* lBs)
{
    const int tid = threadIdx.x;
    const int lane = tid & 63, wave = tid >> 6;
    const int quad = lane >> 4, l15 = lane & 15;
    const int wm = wave >> 1, wn = wave & 1;
    const int r0 = blockIdx.y * 128;
    const int n0 = blockIdx.x * 128;

    floatx4 acc[4][4];
    #pragma unroll
    for (int m = 0; m < 4; m++)
        #pragma unroll
        for (int n = 0; n < 4; n++) acc[m][n] = (floatx4){0.f, 0.f, 0.f, 0.f};

    for (int kb = 0; kb < DD / 64; ++kb) {
        const int k0 = kb * 64;
        __syncthreads();
        #pragma unroll
        for (int i = 0; i < 4; i++) {
            int idx = tid + i * 256;          // 0..1023 chunks of 8 elems
            int r = idx >> 3, c = idx & 7;
            int gc = c ^ (r & 7);             // XOR swizzle
            size_t aoff = (size_t)(r0 + r) * DD + k0 + gc * 8;
            bf16x8 va;
            if (ISBF) {
                va = *(const bf16x8*)((const ushort_t*)A + aoff);
            } else {
                const float* Af = (const float*)A;
                floatx4 f0 = *(const floatx4*)(Af + aoff);
                floatx4 f1 = *(const floatx4*)(Af + aoff + 4);
                union { ushort_t u[8]; bf16x8 v; } t;
                #pragma unroll
                for (int j = 0; j < 4; j++) { t.u[j] = f2bf(f0[j]); t.u[4 + j] = f2bf(f1[j]); }
                va = t.v;
            }
            *(bf16x8*)(lAs + r * 64 + c * 8) = va;
            bf16x8 vb = *(const bf16x8*)(Wt + (size_t)(n0 + r) * DD + k0 + gc * 8);
            *(bf16x8*)(lBs + r * 64 + c * 8) = vb;
        }
        __syncthreads();
        #pragma unroll
        for (int kc = 0; kc < 2; kc++) {
            bf16x8 af[4], bfr[4];
            #pragma unroll
            for (int m = 0; m < 4; m++) {
                int row = wm * 64 + m * 16 + l15;
                int chunk = (kc * 4 + quad) ^ (row & 7);
                af[m] = *(const bf16x8*)(lAs + row * 64 + chunk * 8);
            }
            #pragma unroll
            for (int n = 0; n < 4; n++) {
                int row = wn * 64 + n * 16 + l15;
                int chunk = (kc * 4 + quad) ^ (row & 7);
                bfr[n] = *(const bf16x8*)(lBs + row * 64 + chunk * 8);
            }
            #pragma unroll
            for (int m = 0; m < 4; m++)
                #pragma unroll
                for (int n = 0; n < 4; n++)
                    acc[m][n] = __builtin_amdgcn_mfma_f32_16x16x32_bf16(af[m], bfr[n], acc[m][n], 0, 0, 0);
        }
    }
    #pragma unroll
    for (int n = 0; n < 4; n++) {
        int E = n0 + wn * 64 + n * 16 + l15;
        float bv = ldf<ISBF>(bias, E);
        int h = E >> 6, dk = E & 63;
        #pragma unroll
        for (int m = 0; m < 4; m++) {
            #pragma unroll
            for (int j = 0; j < 4; j++) {
                int R = r0 + wm * 64 + m * 16 + quad * 4 + j;
                int b = R >> 11, s = R & 2047;
                float v = acc[m][n][j] + bv;
                outp[(((size_t)(b * HH + h)) * SS + s) * DKK + dk] = f2bf(v);
            }
        }
    }
}
__global__ __launch_bounds__(256, 2) void gemm_proj(
    const void* A, const ushort_t* Wt, const void* bias, ushort_t* outp, const int* flag)
{
    __shared__ __align__(16) ushort_t lAs[128 * 64];
    __shared__ __align__(16) ushort_t lBs[128 * 64];
    if (*flag) gemm_body<1>(A, Wt, bias, outp, lAs, lBs);
    else       gemm_body<0>(A, Wt, bias, outp, lAs, lBs);
}

// ---------------- aspect path: a = aspect@Wd+bd ; am = a@weight_m[h] --------
template<int ISBF>
__device__ void aspect_body(const void* __restrict__ aspect, const void* __restrict__ Wd,
                            const void* __restrict__ bd, const void* __restrict__ wm,
                            float* __restrict__ am_out, float* a_sh)
{
    int tid = threadIdx.x;
    if (tid < BB * DKK) {
        int b = tid >> 6, dk = tid & 63;
        float s = 0.f;
        for (int d = 0; d < DD; ++d)
            s += ldf<ISBF>(aspect, b * DD + d) * ldf<ISBF>(Wd, (size_t)d * DKK + dk);
        s += ldf<ISBF>(bd, dk);
        a_sh[tid] = s;
    }
    __syncthreads();
    for (int idx = tid; idx < BB * HH * DKK; idx += 256) {
        int b = idx / (HH * DKK);
        int rem = idx - b * (HH * DKK);
        int h = rem >> 6, e = rem & 63;
        float s = 0.f;
        for (int dk = 0; dk < DKK; ++dk)
            s += a_sh[b * DKK + dk] * ldf<ISBF>(wm, (size_t)(h * DKK + dk) * DKK + e);
        am_out[idx] = s;
    }
}
__global__ void aspect_am(const void* aspect, const void* Wd, const void* bd,
                          const void* wm, float* am_out, const int* flag) {
    __shared__ float a_sh[BB * DKK];
    if (*flag) aspect_body<1>(aspect, Wd, bd, wm, am_out, a_sh);
    else       aspect_body<0>(aspect, Wd, bd, wm, am_out, a_sh);
}

// ---------------- ascore[b,h,t] = tanh(am . k[b,h,t,:] + bias_m) ------------
template<int ISBF>
__device__ void ascore_body(const float* __restrict__ am, const ushort_t* __restrict__ kws,
                            const void* __restrict__ bias_m, float* __restrict__ asc) {
    int idx = blockIdx.x * 256 + threadIdx.x;
    if (idx >= BH * SS) return;
    int bh = idx >> 11;
    int t = idx & 2047;
    const float* amv = am + bh * DKK;
    const ushort_t* kp = kws + ((size_t)bh * SS + t) * DKK;
    float s = 0.f;
    #pragma unroll 8
    for (int e = 0; e < DKK; e++) s += amv[e] * bf2f(kp[e]);
    s += ldf<ISBF>(bias_m, 0);
    asc[idx] = tanhf(s);
}
__global__ void ascore_k(const float* am, const ushort_t* kws, const void* bias_m,
                         float* asc, const int* flag) {
    if (*flag) ascore_body<1>(am, kws, bias_m, asc);
    else       ascore_body<0>(am, kws, bias_m, asc);
}

// ---------------- fused scores + mask + short + softmax ---------------------
// 1024 threads / block = 16 waves. Each wave owns 128 columns -> acc[8]
// (32 VGPRs of accumulator vs 128 before) -> target <128 VGPR so 4 waves/SIMD
// (16 waves/CU) instead of 2. Memory-latency hiding via TLP is the goal.
template<int ISBF>
__device__ void scores_body(const ushort_t* __restrict__ qws, const ushort_t* __restrict__ kws,
                            const float* __restrict__ asc, const int* __restrict__ mask,
                            const void* __restrict__ shr, void* __restrict__ outv,
                            float (*red)[16])
{
    const int tid = threadIdx.x;
    const int lane = tid & 63, wave = tid >> 6;       // wave 0..15
    const int quad = lane >> 4, l15 = lane & 15;
    const int r0 = blockIdx.x * 16;
    const int bh = blockIdx.y;
    const int b = bh / HH;

    const ushort_t* qp = qws + ((size_t)bh * SS + r0) * DKK;
    const ushort_t* kp = kws + ((size_t)bh * SS) * DKK;

    bf16x8 aq0 = *(const bf16x8*)(qp + l15 * DKK + quad * 8);
    bf16x8 aq1 = *(const bf16x8*)(qp + l15 * DKK + 32 + quad * 8);

    const int c0 = wave * 128;
    floatx4 acc[8];
    #pragma unroll
    for (int i = 0; i < 8; i++) {
        const ushort_t* kt = kp + (size_t)(c0 + i * 16 + l15) * DKK + quad * 8;
        bf16x8 b0 = *(const bf16x8*)(kt);
        bf16x8 b1 = *(const bf16x8*)(kt + 32);
        floatx4 a = (floatx4){0.f, 0.f, 0.f, 0.f};
        a = __builtin_amdgcn_mfma_f32_16x16x32_bf16(aq0, b0, a, 0, 0, 0);
        a = __builtin_amdgcn_mfma_f32_16x16x32_bf16(aq1, b1, a, 0, 0, 0);
        acc[i] = a;
    }

    float mx[4] = {-3.0e38f, -3.0e38f, -3.0e38f, -3.0e38f};
    const float* ascp = asc + bh * SS;
    #pragma unroll
    for (int i = 0; i < 8; i++) {
        int ct = c0 + i * 16 + l15;
        float av = ascp[ct];
        #pragma unroll
        for (int j = 0; j < 4; j++) {
            int r = r0 + quad * 4 + j;
            int mk = mask[((size_t)(b * SS + r)) * SS + ct];
            float sv = ldf<ISBF>(shr, ((size_t)(bh * SS + r)) * SS + ct);
            float s = (mk == 0) ? -1e9f : (acc[i][j] * 0.125f + av);
            s += sv;
            acc[i][j] = s;
            mx[j] = fmaxf(mx[j], s);
        }
    }
    #pragma unroll
    for (int j = 0; j < 4; j++)
        #pragma unroll
        for (int off = 1; off < 16; off <<= 1)
            mx[j] = fmaxf(mx[j], __shfl_xor(mx[j], off));

    if (l15 == 0) {
        #pragma unroll
        for (int j = 0; j < 4; j++) red[wave][quad * 4 + j] = mx[j];
    }
    __syncthreads();
    float rmax[4];
    #pragma unroll
    for (int j = 0; j < 4; j++) {
        int row = quad * 4 + j;
        float m = red[0][row];
        #pragma unroll
        for (int w = 1; w < 16; w++) m = fmaxf(m, red[w][row]);
        rmax[j] = m;
    }
    __syncthreads();

    float sm[4] = {0.f, 0.f, 0.f, 0.f};
    #pragma unroll
    for (int i = 0; i < 8; i++)
        #pragma unroll
        for (int j = 0; j < 4; j++) {
            float p = __expf(acc[i][j] - rmax[j]);
            acc[i][j] = p;
            sm[j] += p;
        }
    #pragma unroll
    for (int j = 0; j < 4; j++)
        #pragma unroll
        for (int off = 1; off < 16; off <<= 1)
            sm[j] += __shfl_xor(sm[j], off);
    if (l15 == 0) {
        #pragma unroll
        for (int j = 0; j < 4; j++) red[wave][quad * 4 + j] = sm[j];
    }
    __syncthreads();
    float rinv[4];
    #pragma unroll
    for (int j = 0; j < 4; j++) {
        int row = quad * 4 + j;
        float s = red[0][row];
        #pragma unroll
        for (int w = 1; w < 16; w++) s += red[w][row];
        rinv[j] = 1.0f / s;
    }

    #pragma unroll
    for (int i = 0; i < 8; i++) {
        int ct = c0 + i * 16 + l15;
        #pragma unroll
        for (int j = 0; j < 4; j++) {
            int r = r0 + quad * 4 + j;
            size_t oidx = ((size_t)(bh * SS + r)) * SS + ct;
            float v = acc[i][j] * rinv[j];
            if (ISBF) ((ushort_t*)outv)[oidx] = f2bf(v);
            else      ((float*)outv)[oidx] = v;
        }
    }
}
__global__ __launch_bounds__(1024, 4) void scores_softmax(
    const ushort_t* qws, const ushort_t* kws, const float* asc, const int* mask,
    const void* shr, void* outv, const int* flag)
{
    __shared__ float red[16][16];
    if (*flag) scores_body<1>(qws, kws, asc, mask, shr, outv, red);
    else       scores_body<0>(qws, kws, asc, mask, shr, outv, red);
}

extern "C" void kernel_launch(void* const* d_in, const int* in_sizes, int n_in,
                              void* d_out, int out_size, void* d_ws, size_t ws_size,
                              hipStream_t stream) {
    const void* query  = d_in[0];
    const void* key    = d_in[1];
    const int*  mask   = (const int*)d_in[2];
    const void* shr    = d_in[3];
    const void* aspect = d_in[4];
    const void* Wq     = d_in[5];
    const void* bq     = d_in[6];
    const void* Wk     = d_in[7];
    const void* bk     = d_in[8];
    const void* Wd     = d_in[9];
    const void* bd     = d_in[10];
    const void* wm     = d_in[11];
    const void* bias_m = d_in[12];

    char* ws = (char*)d_ws;
    const size_t QK_BYTES = (size_t)BH * SS * DKK * 2;   // 6291456
    const size_t WT_BYTES = (size_t)DD * DD * 2;         // 1179648
    ushort_t* qws = (ushort_t*)(ws);
    ushort_t* kws = (ushort_t*)(ws + QK_BYTES);
    ushort_t* wtq = (ushort_t*)(ws + 2 * QK_BYTES);
    ushort_t* wtk = (ushort_t*)(ws + 2 * QK_BYTES + WT_BYTES);
    float*    amb = (float*)   (ws + 2 * QK_BYTES + 2 * WT_BYTES);
    float*    asc = (float*)   (ws + 2 * QK_BYTES + 2 * WT_BYTES + 8192);
    int*      flg = (int*)     (ws + 2 * QK_BYTES + 2 * WT_BYTES + 8192 + (size_t)BH * SS * 4);

    detect_dtype<<<1, 256, 0, stream>>>((const ushort_t*)query, flg);
    transpose_w<<<dim3((DD * DD + 255) / 256), 256, 0, stream>>>(Wq, wtq, flg);
    transpose_w<<<dim3((DD * DD + 255) / 256), 256, 0, stream>>>(Wk, wtk, flg);
    gemm_proj<<<dim3(DD / 128, (BB * SS) / 128), 256, 0, stream>>>(query, wtq, bq, qws, flg);
    gemm_proj<<<dim3(DD / 128, (BB * SS) / 128), 256, 0, stream>>>(key,   wtk, bk, kws, flg);
    aspect_am<<<1, 256, 0, stream>>>(aspect, Wd, bd, wm, amb, flg);
    ascore_k<<<dim3((BH * SS + 255) / 256), 256, 0, stream>>>(amb, kws, bias_m, asc, flg);
    scores_softmax<<<dim3(SS / 16, BH), 1024, 0, stream>>>(qws, kws, asc, mask, shr, d_out, flg);
}